// Round 16
// baseline (199.868 us; speedup 1.0000x reference)
//
#include <hip/hip_runtime.h>
#include <math.h>

#define NN 20000
#define NE 640000

typedef __attribute__((ext_vector_type(8))) short short8v;
typedef __attribute__((ext_vector_type(4))) float f32x4;

__device__ inline unsigned short f2bf(float f) {
    unsigned int u = __builtin_bit_cast(unsigned int, f);
    u += 0x7fff + ((u >> 16) & 1);   // RNE
    return (unsigned short)(u >> 16);
}
__device__ inline float bf2f(unsigned short s) {
    unsigned int u = ((unsigned int)s) << 16;
    return __builtin_bit_cast(float, u);
}
// async global->LDS, 16B per lane; dest = uniform base + lane*16
__device__ inline void gload16(const unsigned short* g, short* l) {
    __builtin_amdgcn_global_load_lds(
        (const __attribute__((address_space(1))) unsigned int*)g,
        (__attribute__((address_space(3))) unsigned int*)l, 16, 0, 0);
}

// ---- merged enc (blocks 0..312) + prep (blocks 313..1336) ----
__global__ __launch_bounds__(512)
void enc_prep(const float* __restrict__ x, const float* __restrict__ h,
              const float* __restrict__ W_enc, const float* __restrict__ b_enc,
              const float* __restrict__ W_ih, const float* __restrict__ W_hh,
              const float* __restrict__ W_dec, const float* __restrict__ b_ih,
              const float* __restrict__ b_hh, const float* __restrict__ b_dec,
              unsigned short* __restrict__ LdiffBf, unsigned short* __restrict__ Abig,
              unsigned short* __restrict__ Wbig, float* __restrict__ bias_cat,
              unsigned int* __restrict__ cbits)
{
    const int tid = threadIdx.x;       // 0..511
    if (blockIdx.x >= 313) {
        // ---------------- prep ----------------
        const int r = blockIdx.x - 313;          // 0..1023
        int zi = r * 512 + tid;
        if (zi < NN * 4) cbits[zi] = 0u;
        const int g = r >> 8, j = r & 255;
        {   // Wbig x/h columns (k = tid, 0..511)
            float v;
            if (tid < 256) {
                v = (g < 3) ? W_ih[(size_t)(g * 256 + j) * 384 + tid] : 0.f;
            } else {
                int sr = (g < 2) ? g * 256 + j : 512 + j;
                v = (g == 2) ? 0.f : W_hh[(size_t)sr * 256 + (tid - 256)];
            }
            Wbig[(size_t)r * 640 + tid] = f2bf(v);
        }
        if (tid < 128) {                 // c-cols: (W_ih[:,256:] @ W_dec)[r][tid]
            float acc = 0.f;
            if (g < 3) {
                const float* wr = W_ih + (size_t)(g * 256 + j) * 384 + 256;
#pragma unroll 4
                for (int p = 0; p < 128; ++p) acc += wr[p] * W_dec[p * 128 + tid];
            }
            Wbig[(size_t)r * 640 + 512 + tid] = f2bf(acc);
        } else if (tid < 192) {          // bias: one full wave, shfl-reduce
            int m = tid - 128;           // lane 0..63
            float v = 0.f;
            if (g < 3) {
                const float* wr = W_ih + (size_t)(g * 256 + j) * 384 + 256;
                v = wr[m] * b_dec[m] + wr[m + 64] * b_dec[m + 64];
            }
#pragma unroll
            for (int o = 1; o < 64; o <<= 1) v += __shfl_xor(v, o);
            if (m == 0) {
                float bv;
                if (g == 3) bv = b_hh[512 + j];
                else {
                    int sr = g * 256 + j;
                    bv = b_ih[sr] + v + ((g < 2) ? b_hh[sr] : 0.f);
                }
                bias_cat[r] = bv;
            }
        }
        return;
    }
    // ---------------- enc ----------------
    __shared__ __align__(16) short Ah[64][72], Al[64][72];
    __shared__ __align__(16) short Wh[128 * 64], Wl[128 * 64];
    const int bm0 = blockIdx.x * 64;
    const int lane = tid & 63;
    const int wave = tid >> 6;
    const int wm = wave >> 2, wn = wave & 3;   // wave: 32 rows x 32 cols
    const int r16 = lane & 15, kg = lane >> 4;
    const int sw = r16 & 7;

    const int arow = tid >> 3, as_ = tid & 7;
    const int agm = (bm0 + arow >= NN) ? NN - 1 : bm0 + arow;
    const int wrow0 = tid >> 3, wrow1 = (tid >> 3) + 64, ws_ = tid & 7;

    f32x4 acc[2][2];
#pragma unroll
    for (int i = 0; i < 2; ++i)
#pragma unroll
        for (int j = 0; j < 2; ++j) acc[i][j] = (f32x4){0.f, 0.f, 0.f, 0.f};

    float4 av0, av1, wv0, wv1, wv2, wv3;
    auto ISSUE = [&](int kt) {
        int kc = kt * 64 + as_ * 8;
        const float* p = (kc < 256) ? (x + (size_t)agm * 256 + kc)
                                    : (h + (size_t)agm * 256 + (kc - 256));
        av0 = *(const float4*)p;
        av1 = *(const float4*)(p + 4);
        const float* q0 = W_enc + (size_t)wrow0 * 512 + kt * 64 + ws_ * 8;
        const float* q1 = W_enc + (size_t)wrow1 * 512 + kt * 64 + ws_ * 8;
        wv0 = *(const float4*)q0; wv1 = *(const float4*)(q0 + 4);
        wv2 = *(const float4*)q1; wv3 = *(const float4*)(q1 + 4);
    };

    ISSUE(0);
    for (int kt = 0; kt < 8; ++kt) {
        __syncthreads();
        {
            float vv[8] = {av0.x, av0.y, av0.z, av0.w, av1.x, av1.y, av1.z, av1.w};
            short8v hi, lo;
#pragma unroll
            for (int t = 0; t < 8; ++t) {
                unsigned short hb = f2bf(vv[t]);
                hi[t] = (short)hb;
                lo[t] = (short)f2bf(vv[t] - bf2f(hb));
            }
            *(short8v*)&Ah[arow][as_ * 8] = hi;
            *(short8v*)&Al[arow][as_ * 8] = lo;
            *(short8v*)&Abig[(size_t)agm * 512 + kt * 64 + as_ * 8] = hi;
            float ww0[8] = {wv0.x, wv0.y, wv0.z, wv0.w, wv1.x, wv1.y, wv1.z, wv1.w};
            float ww1[8] = {wv2.x, wv2.y, wv2.z, wv2.w, wv3.x, wv3.y, wv3.z, wv3.w};
            short8v h0, l0, h1, l1;
#pragma unroll
            for (int t = 0; t < 8; ++t) {
                unsigned short hb0 = f2bf(ww0[t]);
                h0[t] = (short)hb0; l0[t] = (short)f2bf(ww0[t] - bf2f(hb0));
                unsigned short hb1 = f2bf(ww1[t]);
                h1[t] = (short)hb1; l1[t] = (short)f2bf(ww1[t] - bf2f(hb1));
            }
            int p0 = (ws_ ^ (wrow0 & 7)) * 8;
            int p1 = (ws_ ^ (wrow1 & 7)) * 8;
            *(short8v*)&Wh[wrow0 * 64 + p0] = h0;
            *(short8v*)&Wl[wrow0 * 64 + p0] = l0;
            *(short8v*)&Wh[wrow1 * 64 + p1] = h1;
            *(short8v*)&Wl[wrow1 * 64 + p1] = l1;
        }
        if (kt < 7) ISSUE(kt + 1);
        __syncthreads();
#pragma unroll
        for (int ks = 0; ks < 2; ++ks) {
            int kc = ks * 32 + kg * 8;
            int gsel = (ks * 4 + kg) ^ sw;
            short8v ah[2], al[2], wh[2], wl[2];
#pragma unroll
            for (int f = 0; f < 2; ++f) {
                ah[f] = *(const short8v*)&Ah[wm * 32 + f * 16 + r16][kc];
                al[f] = *(const short8v*)&Al[wm * 32 + f * 16 + r16][kc];
                int wr = wn * 32 + f * 16 + r16;
                wh[f] = *(const short8v*)&Wh[wr * 64 + gsel * 8];
                wl[f] = *(const short8v*)&Wl[wr * 64 + gsel * 8];
            }
#pragma unroll
            for (int fi = 0; fi < 2; ++fi)
#pragma unroll
                for (int fj = 0; fj < 2; ++fj) {
                    acc[fi][fj] = __builtin_amdgcn_mfma_f32_16x16x32_bf16(
                        ah[fi], wh[fj], acc[fi][fj], 0, 0, 0);
                    acc[fi][fj] = __builtin_amdgcn_mfma_f32_16x16x32_bf16(
                        al[fi], wh[fj], acc[fi][fj], 0, 0, 0);
                    acc[fi][fj] = __builtin_amdgcn_mfma_f32_16x16x32_bf16(
                        ah[fi], wl[fj], acc[fi][fj], 0, 0, 0);
                }
        }
    }
    // epilogue: Ldiff (bf16) via shfl_xor over adjacent columns
#pragma unroll
    for (int fi = 0; fi < 2; ++fi) {
        int rg = bm0 + wm * 32 + fi * 16 + kg * 4;
#pragma unroll
        for (int fj = 0; fj < 2; ++fj) {
            int cg = wn * 32 + fj * 16 + r16;
            float bv = b_enc[cg];
#pragma unroll
            for (int i = 0; i < 4; ++i) {
                float v = acc[fi][fj][i] + bv;
                float o = __shfl_xor(v, 1);
                if (!(r16 & 1) && rg + i < NN)
                    LdiffBf[(size_t)(rg + i) * 64 + (cg >> 1)] = f2bf(v - o);
            }
        }
    }
}

// ---- merged: edge (blocks 0..2047, exact R13) + gates-xh (blocks 2048..3299) ----
// The two roles are independent (gates-xh needs only Abig/Wbig; edge writes
// cbits) -> the scheduler co-schedules them; gates compute hides in edge's
// memory-latency slack. gates-xh writes bf16 pre-activations for all 4 gates.
__global__ __launch_bounds__(256)
void edge_gatesxh(const unsigned short* __restrict__ LdiffBf,
                  const float* __restrict__ gumbel,
                  const int* __restrict__ src, const int* __restrict__ dst,
                  unsigned long long* __restrict__ cbits64,
                  const unsigned short* __restrict__ Abig,
                  const unsigned short* __restrict__ Wbig,
                  unsigned short* __restrict__ preact, int E)
{
    const int tid = threadIdx.x;
    if (blockIdx.x < 2048) {
        // ---------------- edge role (exact R13) ----------------
        const int lane = tid & 63;
        const int hl = lane & 31;
        const int side = lane >> 5;
        const int slot = blockIdx.x * 4 + (tid >> 6);
        const int nslots = 2048 * 4;
        const unsigned int* Lw = (const unsigned int*)LdiffBf;

        int p0 = slot;
        if (p0 * 2 >= E) return;
        int e0 = p0 * 2 + side;
        int s0 = src[e0], d0n = dst[e0];
        f32x4 g0 = __builtin_nontemporal_load(
            (const f32x4*)&gumbel[(size_t)e0 * 128 + hl * 4]);
        unsigned int L0 = Lw[(size_t)s0 * 32 + hl];
        int p1 = p0 + nslots;
        int s1 = 0, d1n = 0;
        if (p1 * 2 < E) { int e1 = p1 * 2 + side; s1 = src[e1]; d1n = dst[e1]; }

        while (true) {
            const bool more1 = p1 * 2 < E;
            f32x4 g1; unsigned int L1 = 0;
            if (more1) {
                int e1 = p1 * 2 + side;
                g1 = __builtin_nontemporal_load(
                    (const f32x4*)&gumbel[(size_t)e1 * 128 + hl * 4]);
                L1 = Lw[(size_t)s1 * 32 + hl];
            }
            int p2 = p1 + nslots;
            int s2 = 0, d2n = 0;
            if (p2 * 2 < E) { int e2 = p2 * 2 + side; s2 = src[e2]; d2n = dst[e2]; }
            float da = bf2f((unsigned short)(L0 & 0xffffu));
            float db = bf2f((unsigned short)(L0 >> 16));
            int c0 = (da + g0[0]) < g0[1] ? 1 : 0;
            int c1 = (db + g0[2]) < g0[3] ? 1 : 0;
            int sh = (hl & 7) * 4;
            unsigned int val = (1u << (sh + c0)) | (1u << (sh + 2 + c1));
            val |= __shfl_xor(val, 1);
            val |= __shfl_xor(val, 2);
            val |= __shfl_xor(val, 4);
            unsigned int hiw = __shfl_xor(val, 8);
            if ((hl & 15) == 0)
                atomicOr(&cbits64[(size_t)d0n * 2 + (hl >> 4)],
                         (unsigned long long)val | ((unsigned long long)hiw << 32));
            if (!more1) break;
            p0 = p1; s0 = s1; d0n = d1n; g0 = g1; L0 = L1;
            p1 = p2; s1 = s2; d1n = d2n;
        }
        return;
    }
    // ---------------- gates-xh role ----------------
    __shared__ __align__(16) short As[2][64 * 64];    // 2 x 8 KB
    const int orig = blockIdx.x - 2048;                // 0..1251; q=156, r=4
    const int xcd = orig & 7, idx = orig >> 3;
    const int wgid = (xcd < 4 ? xcd * 157 : 628 + (xcd - 4) * 156) + idx;
    const int bm0 = (wgid >> 2) * 64;
    const int j0  = (wgid & 3) * 64;
    const int lane = tid & 63;
    const int w = tid >> 6;
    const int r16 = lane & 15, kg = lane >> 4;
    const int sw = r16 & 7;

    f32x4 acc[4][4];
#pragma unroll
    for (int g = 0; g < 4; ++g)
#pragma unroll
        for (int i = 0; i < 4; ++i) acc[g][i] = (f32x4){0.f, 0.f, 0.f, 0.f};

    auto STAGE = [&](int b, int kt) {
        const int kc0 = kt * 64;
#pragma unroll
        for (int it = 0; it < 2; ++it) {
            int chunk = w * 2 + it;
            int slot = chunk * 64 + lane;
            int row = slot >> 3, gch = slot & 7;
            int gm = bm0 + row; if (gm >= NN) gm = NN - 1;
            gload16(Abig + (size_t)gm * 512 + kc0 + ((gch ^ (row & 7)) << 3),
                    As[b] + chunk * 512);
        }
    };
    short8v breg[2][3][2];
    auto BLOAD = [&](int b, int kt) {
        const int kc0 = kt * 64;
        const int g2 = (kt < 4) ? 2 : 3;
#pragma unroll
        for (int s = 0; s < 3; ++s) {
            int gate = (s < 2) ? s : g2;
            const unsigned short* bp =
                Wbig + (size_t)(gate * 256 + j0 + w * 16 + r16) * 640 + kc0 + kg * 8;
            breg[b][s][0] = *(const short8v*)bp;
            breg[b][s][1] = *(const short8v*)(bp + 32);
        }
    };

    STAGE(0, 0);
    BLOAD(0, 0);
#pragma unroll
    for (int kt = 0; kt < 8; ++kt) {
        const int cur = kt & 1;
        if (kt < 7) {
            STAGE(cur ^ 1, kt + 1);
            BLOAD(cur ^ 1, kt + 1);
            asm volatile("s_waitcnt vmcnt(8)" ::: "memory");
        } else {
            asm volatile("s_waitcnt vmcnt(0)" ::: "memory");
        }
        __builtin_amdgcn_s_barrier();
        __builtin_amdgcn_sched_barrier(0);
        const int g2c = (kt < 4) ? 2 : 3;
        __builtin_amdgcn_s_setprio(1);
#pragma unroll
        for (int ks = 0; ks < 2; ++ks) {
            int gsel = (ks * 4 + kg) ^ sw;
            short8v a[4];
#pragma unroll
            for (int fi = 0; fi < 4; ++fi)
                a[fi] = *(const short8v*)&As[cur][(fi * 16 + r16) * 64 + gsel * 8];
#pragma unroll
            for (int s = 0; s < 3; ++s) {
                const int gate = (s < 2) ? s : g2c;
#pragma unroll
                for (int fi = 0; fi < 4; ++fi)
                    acc[gate][fi] = __builtin_amdgcn_mfma_f32_16x16x32_bf16(
                        a[fi], breg[cur][s][ks], acc[gate][fi], 0, 0, 0);
            }
        }
        __builtin_amdgcn_s_setprio(0);
        __builtin_amdgcn_sched_barrier(0);
        __builtin_amdgcn_s_barrier();
    }
    // write bf16 pre-activations: preact[m][g*256 + cg]
    const int cg = j0 + w * 16 + r16;
#pragma unroll
    for (int g = 0; g < 4; ++g)
#pragma unroll
        for (int fi = 0; fi < 4; ++fi) {
            int rg = bm0 + fi * 16 + kg * 4;
#pragma unroll
            for (int i = 0; i < 4; ++i) {
                int m = rg + i;
                if (m < NN)
                    __builtin_nontemporal_store(
                        f2bf(acc[g][fi][i]),
                        &preact[(size_t)m * 1024 + g * 256 + cg]);
            }
        }
}

// ---- c-tail + GRU epilogue: acc = preact + c @ Wc^T, then GRU ----
__global__ __launch_bounds__(256)
void gru_ctail(const unsigned short* __restrict__ preact,
               const unsigned int* __restrict__ cbits,
               const unsigned short* __restrict__ Wbig,
               const float* __restrict__ bias_cat,
               const float* __restrict__ h, float* __restrict__ out)
{
    const int wgid = blockIdx.x;                 // 1252
    const int bm0 = (wgid >> 2) * 64;
    const int j0  = (wgid & 3) * 64;
    const int tid = threadIdx.x;
    const int lane = tid & 63;
    const int w = tid >> 6;
    const int r16 = lane & 15, kg = lane >> 4;
    const int cg = j0 + w * 16 + r16;

    // load cbits words (4 rows/thread x 4 words)
    unsigned int cw[4][4];
#pragma unroll
    for (int fi = 0; fi < 4; ++fi) {
        int rr = bm0 + fi * 16 + r16; if (rr >= NN) rr = NN - 1;
        uint4 v = *(const uint4*)&cbits[rr * 4];
        cw[fi][0] = v.x; cw[fi][1] = v.y; cw[fi][2] = v.z; cw[fi][3] = v.w;
    }
    // B c-columns for kt 8,9 (gates r,z,i_n)
    short8v breg[2][3][2];
#pragma unroll
    for (int kt8 = 0; kt8 < 2; ++kt8)
#pragma unroll
        for (int s = 0; s < 3; ++s) {
            const unsigned short* bp =
                Wbig + (size_t)(s * 256 + j0 + w * 16 + r16) * 640 + (8 + kt8) * 64 + kg * 8;
            breg[kt8][s][0] = *(const short8v*)bp;
            breg[kt8][s][1] = *(const short8v*)(bp + 32);
        }
    // init acc from preact
    f32x4 acc[4][4];
#pragma unroll
    for (int g = 0; g < 4; ++g)
#pragma unroll
        for (int fi = 0; fi < 4; ++fi) {
            int rg = bm0 + fi * 16 + kg * 4;
#pragma unroll
            for (int i = 0; i < 4; ++i) {
                int m = rg + i; if (m >= NN) m = NN - 1;
                acc[g][fi][i] = bf2f(preact[(size_t)m * 1024 + g * 256 + cg]);
            }
        }
    // c-tail MFMAs
#pragma unroll
    for (int kt8 = 0; kt8 < 2; ++kt8) {
        short8v a[4][2];
#pragma unroll
        for (int fi = 0; fi < 4; ++fi)
#pragma unroll
            for (int ks = 0; ks < 2; ++ks) {
                unsigned int byte = (cw[fi][kt8 * 2 + ks] >> (kg * 8)) & 0xffu;
                short8v v;
#pragma unroll
                for (int t = 0; t < 8; ++t)
                    v[t] = ((byte >> t) & 1u) ? (short)0x3F80 : (short)0;
                a[fi][ks] = v;
            }
#pragma unroll
        for (int ks = 0; ks < 2; ++ks)
#pragma unroll
            for (int s = 0; s < 3; ++s) {
                const int gate = (s < 2) ? s : 2;
#pragma unroll
                for (int fi = 0; fi < 4; ++fi)
                    acc[gate][fi] = __builtin_amdgcn_mfma_f32_16x16x32_bf16(
                        a[fi][ks], breg[kt8][s][ks], acc[gate][fi], 0, 0, 0);
            }
    }
    // GRU epilogue
    const float br = bias_cat[cg],       bz = bias_cat[256 + cg];
    const float bi = bias_cat[512 + cg], bh = bias_cat[768 + cg];
#pragma unroll
    for (int fi = 0; fi < 4; ++fi) {
        int rg = bm0 + fi * 16 + kg * 4;
#pragma unroll
        for (int i = 0; i < 4; ++i) {
            int m = rg + i;
            if (m >= NN) continue;
            float rp = acc[0][fi][i] + br;
            float zp = acc[1][fi][i] + bz;
            float ip = acc[2][fi][i] + bi;
            float hp = acc[3][fi][i] + bh;
            float hv = h[(size_t)m * 256 + cg];
            float r = 1.f / (1.f + __expf(-rp));
            float z = 1.f / (1.f + __expf(-zp));
            float nn2 = tanhf(ip + r * hp);
            __builtin_nontemporal_store((1.f - z) * nn2 + z * hv,
                                        &out[(size_t)m * 256 + cg]);
        }
    }
}

extern "C" void kernel_launch(void* const* d_in, const int* in_sizes, int n_in,
                              void* d_out, int out_size, void* d_ws, size_t ws_size,
                              hipStream_t stream)
{
    const float* x     = (const float*)d_in[0];
    const float* h     = (const float*)d_in[1];
    const float* W_enc = (const float*)d_in[2];
    const float* b_enc = (const float*)d_in[3];
    const float* W_dec = (const float*)d_in[4];
    const float* b_dec = (const float*)d_in[5];
    const float* W_ih  = (const float*)d_in[6];
    const float* b_ih  = (const float*)d_in[7];
    const float* W_hh  = (const float*)d_in[8];
    const float* b_hh  = (const float*)d_in[9];
    const float* gumbel = (const float*)d_in[10];
    const int*   src   = (const int*)d_in[11];
    const int*   dst   = (const int*)d_in[12];
    float* out = (float*)d_out;

    char* ws = (char*)d_ws;
    unsigned short* LdiffBf  = (unsigned short*)(ws);              //  2,560,000
    unsigned int*   cbits    = (unsigned int*)(ws + 2560000);      //    320,000
    unsigned short* Wbig     = (unsigned short*)(ws + 2880000);    //  1,310,720
    float*          bias_cat = (float*)(ws + 4190720);             //      4,096
    unsigned short* Abig     = (unsigned short*)(ws + 4194816);    // 20,480,000
    unsigned short* preact   = (unsigned short*)(ws + 24674816);   // 40,960,000

    enc_prep<<<1337, 512, 0, stream>>>(x, h, W_enc, b_enc, W_ih, W_hh, W_dec,
                                       b_ih, b_hh, b_dec,
                                       LdiffBf, Abig, Wbig, bias_cat, cbits);
    edge_gatesxh<<<3300, 256, 0, stream>>>(LdiffBf, gumbel, src, dst,
                                           (unsigned long long*)cbits,
                                           Abig, Wbig, preact, NE);
    gru_ctail<<<1252, 256, 0, stream>>>(preact, cbits, Wbig, bias_cat, h, out);
}

// Round 17
// 155.106 us; speedup vs baseline: 1.2886x; 1.2886x over previous
//
#include <hip/hip_runtime.h>
#include <math.h>

#define NN 20000
#define NE 640000

typedef __attribute__((ext_vector_type(8))) short short8v;
typedef __attribute__((ext_vector_type(4))) float f32x4;

__device__ inline unsigned short f2bf(float f) {
    unsigned int u = __builtin_bit_cast(unsigned int, f);
    u += 0x7fff + ((u >> 16) & 1);   // RNE
    return (unsigned short)(u >> 16);
}
__device__ inline float bf2f(unsigned short s) {
    unsigned int u = ((unsigned int)s) << 16;
    return __builtin_bit_cast(float, u);
}
// async global->LDS, 16B per lane; dest = uniform base + lane*16
__device__ inline void gload16(const unsigned short* g, short* l) {
    __builtin_amdgcn_global_load_lds(
        (const __attribute__((address_space(1))) unsigned int*)g,
        (__attribute__((address_space(3))) unsigned int*)l, 16, 0, 0);
}

// ---- merged enc (blocks 0..312) + prep (blocks 313..1336) ----
__global__ __launch_bounds__(512)
void enc_prep(const float* __restrict__ x, const float* __restrict__ h,
              const float* __restrict__ W_enc, const float* __restrict__ b_enc,
              const float* __restrict__ W_ih, const float* __restrict__ W_hh,
              const float* __restrict__ W_dec, const float* __restrict__ b_ih,
              const float* __restrict__ b_hh, const float* __restrict__ b_dec,
              unsigned short* __restrict__ LdiffBf, unsigned short* __restrict__ Abig,
              unsigned short* __restrict__ Wbig, float* __restrict__ bias_cat,
              unsigned int* __restrict__ cbits)
{
    const int tid = threadIdx.x;       // 0..511
    if (blockIdx.x >= 313) {
        // ---------------- prep ----------------
        const int r = blockIdx.x - 313;          // 0..1023
        int zi = r * 512 + tid;
        if (zi < NN * 4) cbits[zi] = 0u;
        const int g = r >> 8, j = r & 255;
        {   // Wbig x/h columns (k = tid, 0..511)
            float v;
            if (tid < 256) {
                v = (g < 3) ? W_ih[(size_t)(g * 256 + j) * 384 + tid] : 0.f;
            } else {
                int sr = (g < 2) ? g * 256 + j : 512 + j;
                v = (g == 2) ? 0.f : W_hh[(size_t)sr * 256 + (tid - 256)];
            }
            Wbig[(size_t)r * 640 + tid] = f2bf(v);
        }
        if (tid < 128) {                 // c-cols: (W_ih[:,256:] @ W_dec)[r][tid]
            float acc = 0.f;
            if (g < 3) {
                const float* wr = W_ih + (size_t)(g * 256 + j) * 384 + 256;
#pragma unroll 4
                for (int p = 0; p < 128; ++p) acc += wr[p] * W_dec[p * 128 + tid];
            }
            Wbig[(size_t)r * 640 + 512 + tid] = f2bf(acc);
        } else if (tid < 192) {          // bias: one full wave, shfl-reduce
            int m = tid - 128;           // lane 0..63
            float v = 0.f;
            if (g < 3) {
                const float* wr = W_ih + (size_t)(g * 256 + j) * 384 + 256;
                v = wr[m] * b_dec[m] + wr[m + 64] * b_dec[m + 64];
            }
#pragma unroll
            for (int o = 1; o < 64; o <<= 1) v += __shfl_xor(v, o);
            if (m == 0) {
                float bv;
                if (g == 3) bv = b_hh[512 + j];
                else {
                    int sr = g * 256 + j;
                    bv = b_ih[sr] + v + ((g < 2) ? b_hh[sr] : 0.f);
                }
                bias_cat[r] = bv;
            }
        }
        return;
    }
    // ---------------- enc ----------------
    __shared__ __align__(16) short Ah[64][72], Al[64][72];
    __shared__ __align__(16) short Wh[128 * 64], Wl[128 * 64];
    const int bm0 = blockIdx.x * 64;
    const int lane = tid & 63;
    const int wave = tid >> 6;
    const int wm = wave >> 2, wn = wave & 3;   // wave: 32 rows x 32 cols
    const int r16 = lane & 15, kg = lane >> 4;
    const int sw = r16 & 7;

    const int arow = tid >> 3, as_ = tid & 7;
    const int agm = (bm0 + arow >= NN) ? NN - 1 : bm0 + arow;
    const int wrow0 = tid >> 3, wrow1 = (tid >> 3) + 64, ws_ = tid & 7;

    f32x4 acc[2][2];
#pragma unroll
    for (int i = 0; i < 2; ++i)
#pragma unroll
        for (int j = 0; j < 2; ++j) acc[i][j] = (f32x4){0.f, 0.f, 0.f, 0.f};

    float4 av0, av1, wv0, wv1, wv2, wv3;
    auto ISSUE = [&](int kt) {
        int kc = kt * 64 + as_ * 8;
        const float* p = (kc < 256) ? (x + (size_t)agm * 256 + kc)
                                    : (h + (size_t)agm * 256 + (kc - 256));
        av0 = *(const float4*)p;
        av1 = *(const float4*)(p + 4);
        const float* q0 = W_enc + (size_t)wrow0 * 512 + kt * 64 + ws_ * 8;
        const float* q1 = W_enc + (size_t)wrow1 * 512 + kt * 64 + ws_ * 8;
        wv0 = *(const float4*)q0; wv1 = *(const float4*)(q0 + 4);
        wv2 = *(const float4*)q1; wv3 = *(const float4*)(q1 + 4);
    };

    ISSUE(0);
    for (int kt = 0; kt < 8; ++kt) {
        __syncthreads();
        {
            float vv[8] = {av0.x, av0.y, av0.z, av0.w, av1.x, av1.y, av1.z, av1.w};
            short8v hi, lo;
#pragma unroll
            for (int t = 0; t < 8; ++t) {
                unsigned short hb = f2bf(vv[t]);
                hi[t] = (short)hb;
                lo[t] = (short)f2bf(vv[t] - bf2f(hb));
            }
            *(short8v*)&Ah[arow][as_ * 8] = hi;
            *(short8v*)&Al[arow][as_ * 8] = lo;
            *(short8v*)&Abig[(size_t)agm * 512 + kt * 64 + as_ * 8] = hi;
            float ww0[8] = {wv0.x, wv0.y, wv0.z, wv0.w, wv1.x, wv1.y, wv1.z, wv1.w};
            float ww1[8] = {wv2.x, wv2.y, wv2.z, wv2.w, wv3.x, wv3.y, wv3.z, wv3.w};
            short8v h0, l0, h1, l1;
#pragma unroll
            for (int t = 0; t < 8; ++t) {
                unsigned short hb0 = f2bf(ww0[t]);
                h0[t] = (short)hb0; l0[t] = (short)f2bf(ww0[t] - bf2f(hb0));
                unsigned short hb1 = f2bf(ww1[t]);
                h1[t] = (short)hb1; l1[t] = (short)f2bf(ww1[t] - bf2f(hb1));
            }
            int p0 = (ws_ ^ (wrow0 & 7)) * 8;
            int p1 = (ws_ ^ (wrow1 & 7)) * 8;
            *(short8v*)&Wh[wrow0 * 64 + p0] = h0;
            *(short8v*)&Wl[wrow0 * 64 + p0] = l0;
            *(short8v*)&Wh[wrow1 * 64 + p1] = h1;
            *(short8v*)&Wl[wrow1 * 64 + p1] = l1;
        }
        if (kt < 7) ISSUE(kt + 1);
        __syncthreads();
#pragma unroll
        for (int ks = 0; ks < 2; ++ks) {
            int kc = ks * 32 + kg * 8;
            int gsel = (ks * 4 + kg) ^ sw;
            short8v ah[2], al[2], wh[2], wl[2];
#pragma unroll
            for (int f = 0; f < 2; ++f) {
                ah[f] = *(const short8v*)&Ah[wm * 32 + f * 16 + r16][kc];
                al[f] = *(const short8v*)&Al[wm * 32 + f * 16 + r16][kc];
                int wr = wn * 32 + f * 16 + r16;
                wh[f] = *(const short8v*)&Wh[wr * 64 + gsel * 8];
                wl[f] = *(const short8v*)&Wl[wr * 64 + gsel * 8];
            }
#pragma unroll
            for (int fi = 0; fi < 2; ++fi)
#pragma unroll
                for (int fj = 0; fj < 2; ++fj) {
                    acc[fi][fj] = __builtin_amdgcn_mfma_f32_16x16x32_bf16(
                        ah[fi], wh[fj], acc[fi][fj], 0, 0, 0);
                    acc[fi][fj] = __builtin_amdgcn_mfma_f32_16x16x32_bf16(
                        al[fi], wh[fj], acc[fi][fj], 0, 0, 0);
                    acc[fi][fj] = __builtin_amdgcn_mfma_f32_16x16x32_bf16(
                        ah[fi], wl[fj], acc[fi][fj], 0, 0, 0);
                }
        }
    }
    // epilogue: Ldiff (bf16) via shfl_xor over adjacent columns
#pragma unroll
    for (int fi = 0; fi < 2; ++fi) {
        int rg = bm0 + wm * 32 + fi * 16 + kg * 4;
#pragma unroll
        for (int fj = 0; fj < 2; ++fj) {
            int cg = wn * 32 + fj * 16 + r16;
            float bv = b_enc[cg];
#pragma unroll
            for (int i = 0; i < 4; ++i) {
                float v = acc[fi][fj][i] + bv;
                float o = __shfl_xor(v, 1);
                if (!(r16 & 1) && rg + i < NN)
                    LdiffBf[(size_t)(rg + i) * 64 + (cg >> 1)] = f2bf(v - o);
            }
        }
    }
}

// ---- edge: 2 edges/wave; nt gumbel loads; u64 atomics; deep prefetch ----
__global__ __launch_bounds__(256)
void edge_msg_kernel(const unsigned short* __restrict__ LdiffBf,
                     const float* __restrict__ gumbel,
                     const int* __restrict__ src, const int* __restrict__ dst,
                     unsigned long long* __restrict__ cbits64, int E)
{
    const int lane = threadIdx.x & 63;
    const int hl = lane & 31;
    const int side = lane >> 5;
    const int slot = blockIdx.x * 4 + (threadIdx.x >> 6);
    const int nslots = gridDim.x * 4;
    const unsigned int* Lw = (const unsigned int*)LdiffBf;

    int p0 = slot;
    if (p0 * 2 >= E) return;
    int e0 = p0 * 2 + side;
    int s0 = src[e0], d0n = dst[e0];
    f32x4 g0 = __builtin_nontemporal_load(
        (const f32x4*)&gumbel[(size_t)e0 * 128 + hl * 4]);
    unsigned int L0 = Lw[(size_t)s0 * 32 + hl];
    int p1 = p0 + nslots;
    int s1 = 0, d1n = 0;
    if (p1 * 2 < E) { int e1 = p1 * 2 + side; s1 = src[e1]; d1n = dst[e1]; }

    while (true) {
        const bool more1 = p1 * 2 < E;
        f32x4 g1; unsigned int L1 = 0;
        if (more1) {
            int e1 = p1 * 2 + side;
            g1 = __builtin_nontemporal_load(
                (const f32x4*)&gumbel[(size_t)e1 * 128 + hl * 4]);
            L1 = Lw[(size_t)s1 * 32 + hl];
        }
        int p2 = p1 + nslots;
        int s2 = 0, d2n = 0;
        if (p2 * 2 < E) { int e2 = p2 * 2 + side; s2 = src[e2]; d2n = dst[e2]; }
        // compute current edge
        float da = bf2f((unsigned short)(L0 & 0xffffu));
        float db = bf2f((unsigned short)(L0 >> 16));
        int c0 = (da + g0[0]) < g0[1] ? 1 : 0;
        int c1 = (db + g0[2]) < g0[3] ? 1 : 0;
        int sh = (hl & 7) * 4;
        unsigned int val = (1u << (sh + c0)) | (1u << (sh + 2 + c1));
        val |= __shfl_xor(val, 1);
        val |= __shfl_xor(val, 2);
        val |= __shfl_xor(val, 4);
        unsigned int hiw = __shfl_xor(val, 8);
        if ((hl & 15) == 0)
            atomicOr(&cbits64[(size_t)d0n * 2 + (hl >> 4)],
                     (unsigned long long)val | ((unsigned long long)hiw << 32));
        if (!more1) break;
        p0 = p1; s0 = s1; d0n = d1n; g0 = g1; L0 = L1;
        p1 = p2; s1 = s2; d1n = d2n;
    }
}

// ---- gates+GRU: dbuf LDS-A + reg-B, XCD swizzle, in-reg c tail ----
__global__ __launch_bounds__(256)
void gates_gru(const unsigned short* __restrict__ Abig,
               const unsigned int* __restrict__ cbits,
               const unsigned short* __restrict__ Wbig,
               const float* __restrict__ bias_cat,
               const float* __restrict__ h, float* __restrict__ out)
{
    __shared__ __align__(16) short As[2][64 * 64];    // 2 x 8 KB
    const int orig = blockIdx.x;                       // 1252; q=156, r=4
    const int xcd = orig & 7, idx = orig >> 3;
    const int wgid = (xcd < 4 ? xcd * 157 : 628 + (xcd - 4) * 156) + idx;
    const int bm0 = (wgid >> 2) * 64;
    const int j0  = (wgid & 3) * 64;
    const int tid = threadIdx.x;
    const int lane = tid & 63;
    const int w = tid >> 6;
    const int r16 = lane & 15, kg = lane >> 4;
    const int sw = r16 & 7;

    f32x4 acc[4][4];
#pragma unroll
    for (int g = 0; g < 4; ++g)
#pragma unroll
        for (int i = 0; i < 4; ++i) acc[g][i] = (f32x4){0.f, 0.f, 0.f, 0.f};

    unsigned int cw[4][4];
#pragma unroll
    for (int fi = 0; fi < 4; ++fi) {
        int rr = bm0 + fi * 16 + r16; if (rr >= NN) rr = NN - 1;
        uint4 v = *(const uint4*)&cbits[rr * 4];
        cw[fi][0] = v.x; cw[fi][1] = v.y; cw[fi][2] = v.z; cw[fi][3] = v.w;
    }

    auto STAGE = [&](int b, int kt) {
        const int kc0 = kt * 64;
#pragma unroll
        for (int it = 0; it < 2; ++it) {
            int chunk = w * 2 + it;
            int slot = chunk * 64 + lane;
            int row = slot >> 3, gch = slot & 7;
            int gm = bm0 + row; if (gm >= NN) gm = NN - 1;
            gload16(Abig + (size_t)gm * 512 + kc0 + ((gch ^ (row & 7)) << 3),
                    As[b] + chunk * 512);
        }
    };
    short8v breg[2][3][2];
    auto BLOAD = [&](int b, int kt) {
        const int kc0 = kt * 64;
        const int g2 = (kt < 4 || kt >= 8) ? 2 : 3;
#pragma unroll
        for (int s = 0; s < 3; ++s) {
            int gate = (s < 2) ? s : g2;
            const unsigned short* bp =
                Wbig + (size_t)(gate * 256 + j0 + w * 16 + r16) * 640 + kc0 + kg * 8;
            breg[b][s][0] = *(const short8v*)bp;
            breg[b][s][1] = *(const short8v*)(bp + 32);
        }
    };

    STAGE(0, 0);
    BLOAD(0, 0);
#pragma unroll
    for (int kt = 0; kt < 8; ++kt) {
        const int cur = kt & 1;
        if (kt < 7) STAGE(cur ^ 1, kt + 1);
        BLOAD(cur ^ 1, kt + 1);
        if (kt < 7) { asm volatile("s_waitcnt vmcnt(8)" ::: "memory"); }
        else        { asm volatile("s_waitcnt vmcnt(6)" ::: "memory"); }
        __builtin_amdgcn_s_barrier();
        __builtin_amdgcn_sched_barrier(0);
        const int g2c = (kt < 4) ? 2 : 3;
        __builtin_amdgcn_s_setprio(1);
#pragma unroll
        for (int ks = 0; ks < 2; ++ks) {
            int gsel = (ks * 4 + kg) ^ sw;
            short8v a[4];
#pragma unroll
            for (int fi = 0; fi < 4; ++fi)
                a[fi] = *(const short8v*)&As[cur][(fi * 16 + r16) * 64 + gsel * 8];
#pragma unroll
            for (int s = 0; s < 3; ++s) {
                const int gate = (s < 2) ? s : g2c;
#pragma unroll
                for (int fi = 0; fi < 4; ++fi)
                    acc[gate][fi] = __builtin_amdgcn_mfma_f32_16x16x32_bf16(
                        a[fi], breg[cur][s][ks], acc[gate][fi], 0, 0, 0);
            }
        }
        __builtin_amdgcn_s_setprio(0);
        __builtin_amdgcn_sched_barrier(0);
        __builtin_amdgcn_s_barrier();
    }
    // c-tail: kt=8 (breg[0]) and kt=9 (breg[1]); gates r,z,i_n
    BLOAD(1, 9);
#pragma unroll
    for (int kt8 = 0; kt8 < 2; ++kt8) {
        short8v a[4][2];
#pragma unroll
        for (int fi = 0; fi < 4; ++fi)
#pragma unroll
            for (int ks = 0; ks < 2; ++ks) {
                unsigned int byte = (cw[fi][kt8 * 2 + ks] >> (kg * 8)) & 0xffu;
                short8v v;
#pragma unroll
                for (int t = 0; t < 8; ++t)
                    v[t] = ((byte >> t) & 1u) ? (short)0x3F80 : (short)0;
                a[fi][ks] = v;
            }
#pragma unroll
        for (int ks = 0; ks < 2; ++ks)
#pragma unroll
            for (int s = 0; s < 3; ++s) {
                const int gate = (s < 2) ? s : 2;
#pragma unroll
                for (int fi = 0; fi < 4; ++fi)
                    acc[gate][fi] = __builtin_amdgcn_mfma_f32_16x16x32_bf16(
                        a[fi][ks], breg[kt8][s][ks], acc[gate][fi], 0, 0, 0);
            }
    }
    // GRU epilogue
    const int cg = j0 + w * 16 + r16;
    const float br = bias_cat[cg],       bz = bias_cat[256 + cg];
    const float bi = bias_cat[512 + cg], bh = bias_cat[768 + cg];
#pragma unroll
    for (int fi = 0; fi < 4; ++fi) {
        int rg = bm0 + fi * 16 + kg * 4;
#pragma unroll
        for (int i = 0; i < 4; ++i) {
            int m = rg + i;
            if (m >= NN) continue;
            float rp = acc[0][fi][i] + br;
            float zp = acc[1][fi][i] + bz;
            float ip = acc[2][fi][i] + bi;
            float hp = acc[3][fi][i] + bh;
            float hv = h[(size_t)m * 256 + cg];
            float r = 1.f / (1.f + __expf(-rp));
            float z = 1.f / (1.f + __expf(-zp));
            float nn2 = tanhf(ip + r * hp);
            out[(size_t)m * 256 + cg] = (1.f - z) * nn2 + z * hv;
        }
    }
}

extern "C" void kernel_launch(void* const* d_in, const int* in_sizes, int n_in,
                              void* d_out, int out_size, void* d_ws, size_t ws_size,
                              hipStream_t stream)
{
    const float* x     = (const float*)d_in[0];
    const float* h     = (const float*)d_in[1];
    const float* W_enc = (const float*)d_in[2];
    const float* b_enc = (const float*)d_in[3];
    const float* W_dec = (const float*)d_in[4];
    const float* b_dec = (const float*)d_in[5];
    const float* W_ih  = (const float*)d_in[6];
    const float* b_ih  = (const float*)d_in[7];
    const float* W_hh  = (const float*)d_in[8];
    const float* b_hh  = (const float*)d_in[9];
    const float* gumbel = (const float*)d_in[10];
    const int*   src   = (const int*)d_in[11];
    const int*   dst   = (const int*)d_in[12];
    float* out = (float*)d_out;

    char* ws = (char*)d_ws;
    unsigned short* LdiffBf  = (unsigned short*)(ws);             //  2,560,000
    unsigned int*   cbits    = (unsigned int*)(ws + 2560000);     //    320,000
    unsigned short* Wbig     = (unsigned short*)(ws + 2880000);   //  1,310,720
    float*          bias_cat = (float*)(ws + 4190720);            //      4,096
    unsigned short* Abig     = (unsigned short*)(ws + 4194816);   // 20,480,000

    enc_prep<<<1337, 512, 0, stream>>>(x, h, W_enc, b_enc, W_ih, W_hh, W_dec,
                                       b_ih, b_hh, b_dec,
                                       LdiffBf, Abig, Wbig, bias_cat, cbits);
    edge_msg_kernel<<<2048, 256, 0, stream>>>(LdiffBf, gumbel, src, dst,
                                              (unsigned long long*)cbits, NE);
    gates_gru<<<1252, 256, 0, stream>>>(Abig, cbits, Wbig, bias_cat, h, out);
}